// Round 1
// baseline (69676.062 us; speedup 1.0000x reference)
//
#include <hip/hip_runtime.h>
#include <hip/hip_cooperative_groups.h>
#include <math.h>

namespace cg = cooperative_groups;

#define L_ 256
#define B_ 128
#define V_ 32000
#define E_ 512
#define H_ 512
#define G_ 1536   // 3*H
#define NT_ 2

__device__ __forceinline__ float sigm(float x) { return 1.0f / (1.0f + __expf(-x)); }

// ---------------------------------------------------------------------------
// Phase A: gxT[dir][l][col][b] = sum_k emb[xs[l][b]][k] * Wx[k][col] + bias[col]
// Tile: 128 cols x 128 b (one l per block), BK=16, 8x8 per thread.
// ---------------------------------------------------------------------------
__global__ __launch_bounds__(256) void gx_kernel(
    const int* __restrict__ xs, const float* __restrict__ emb,
    const float* __restrict__ Wf, const float* __restrict__ bf,
    const float* __restrict__ Wb, const float* __restrict__ bbv,
    float* __restrict__ gxT)
{
  __shared__ float As[16 * 128];   // [kk][col]
  __shared__ float Bs[16 * 132];   // [kk][b] (+4 pad)
  __shared__ int toks[B_];
  const int l = blockIdx.y;
  const int dir = blockIdx.z;
  const int col0 = blockIdx.x * 128;
  const float* __restrict__ Wx = dir ? Wb : Wf;
  const float* __restrict__ bias = dir ? bbv : bf;
  const int t = threadIdx.x;
  if (t < B_) toks[t] = xs[l * B_ + t];
  __syncthreads();
  const int ty = t >> 4, tx = t & 15;
  float acc[8][8];
#pragma unroll
  for (int i = 0; i < 8; i++)
#pragma unroll
    for (int j = 0; j < 8; j++) acc[i][j] = 0.0f;

  for (int k0 = 0; k0 < E_; k0 += 16) {
    {  // stage A slice of Wx: [kk][col] — coalesced along col
      const int kk = t >> 4;
      const int cl = (t & 15) * 8;
      const float* src = Wx + (size_t)(k0 + kk) * G_ + col0 + cl;
      float4 v0 = *(const float4*)(src);
      float4 v1 = *(const float4*)(src + 4);
      *(float4*)(&As[kk * 128 + cl]) = v0;
      *(float4*)(&As[kk * 128 + cl + 4]) = v1;
    }
    {  // stage B: emb gather — lanes walk kk within an emb row (coalesced 64B)
      const int u = t & 15;
      const int v = t >> 4;
#pragma unroll
      for (int i = 0; i < 8; i++) {
        const int b = v * 8 + i;
        Bs[u * 132 + b] = emb[toks[b] * E_ + k0 + u];
      }
    }
    __syncthreads();
#pragma unroll
    for (int kk = 0; kk < 16; kk++) {
      float a[8], bv[8];
      *(float4*)(a)     = *(const float4*)(&As[kk * 128 + ty * 8]);
      *(float4*)(a + 4) = *(const float4*)(&As[kk * 128 + ty * 8 + 4]);
      *(float4*)(bv)     = *(const float4*)(&Bs[kk * 132 + tx * 8]);
      *(float4*)(bv + 4) = *(const float4*)(&Bs[kk * 132 + tx * 8 + 4]);
#pragma unroll
      for (int i = 0; i < 8; i++)
#pragma unroll
        for (int j = 0; j < 8; j++)
          acc[i][j] = fmaf(a[i], bv[j], acc[i][j]);
    }
    __syncthreads();
  }
  const size_t base = ((size_t)dir * L_ + l) * (size_t)G_ * B_;
#pragma unroll
  for (int i = 0; i < 8; i++) {
    const int col = col0 + ty * 8 + i;
    const float bvv = bias[col];
    float4 w0, w1;
    w0.x = acc[i][0] + bvv; w0.y = acc[i][1] + bvv; w0.z = acc[i][2] + bvv; w0.w = acc[i][3] + bvv;
    w1.x = acc[i][4] + bvv; w1.y = acc[i][5] + bvv; w1.z = acc[i][6] + bvv; w1.w = acc[i][7] + bvv;
    float* dst = gxT + base + (size_t)col * B_ + tx * 8;
    *(float4*)(dst)     = w0;
    *(float4*)(dst + 4) = w1;
  }
}

// ---------------------------------------------------------------------------
// Recurrence: persistent cooperative kernel.
// 256 WGs x 256 threads: WG -> (dir = wg&1, idx = wg>>1). Each WG owns h-cols
// J0..J0+3 (i.e. gate columns {g*512+J0+c}) of all 3 per-step GEMMs; weights
// for those 12 columns x 3 phases live in LDS for the whole kernel (72 KB).
// h kept transposed in ws: hT[k][b]. 3 grid syncs per step.
// Thread (rt = t&63, cgp = t>>6): rows {2rt,2rt+1}, h-col j = J0+cgp.
// ---------------------------------------------------------------------------
__global__ __launch_bounds__(256, 1) void rec_kernel(
    const float* __restrict__ gxT, const float* __restrict__ maskp,
    const float* __restrict__ Uhf, const float* __restrict__ Uhb,
    const float* __restrict__ tUf, const float* __restrict__ tUb,
    const float* __restrict__ tbf, const float* __restrict__ tbb,
    float* __restrict__ hstate, float* __restrict__ htmp1,
    float* __restrict__ htmp2, float* __restrict__ outp)
{
  extern __shared__ float sm[];
  float* WL = sm;            // [3 phases][3 gates][4 c][512 k] = 18432 floats
  float* HC = sm + 18432;    // [128 k][128 b] chunk = 16384 floats
  cg::grid_group grid = cg::this_grid();

  const int wg = blockIdx.x;
  const int dir = wg & 1;
  const int idx = wg >> 1;
  const int J0 = idx * 4;
  const int t = threadIdx.x;
  const int rt = t & 63;
  const int cgp = t >> 6;

  const float* __restrict__ Uh = dir ? Uhb : Uhf;
  const float* __restrict__ tU = dir ? tUb : tUf;
  const float* __restrict__ tb = dir ? tbb : tbf;

  // one-time W column-slice load (uncoalesced but once per launch)
  for (int i = t; i < 3 * 3 * 4 * 512; i += 256) {
    const int k = i & 511;
    const int cid = i >> 9;           // (ph*3+g)*4+c
    const int c = cid & 3;
    const int g = (cid >> 2) % 3;
    const int ph = cid / 12;
    const int col = g * 512 + J0 + c;
    WL[i] = (ph == 0) ? Uh[(size_t)k * G_ + col]
                      : tU[((size_t)(ph - 1) * H_ + k) * G_ + col];
  }
  float* hs  = hstate + (size_t)dir * H_ * B_;
  float* h1d = htmp1  + (size_t)dir * H_ * B_;
  float* h2d = htmp2  + (size_t)dir * H_ * B_;
  for (int i = t; i < 4 * B_; i += 256)
    hs[(size_t)(J0 + (i >> 7)) * B_ + (i & 127)] = 0.0f;
  __threadfence();
  grid.sync();

  const int j = J0 + cgp;
  for (int step = 0; step < L_; step++) {
    const int l = dir ? (L_ - 1 - step) : step;
    float hprev0 = 0.f, hprev1 = 0.f, hin0 = 0.f, hin1 = 0.f;
    for (int ph = 0; ph < 3; ph++) {
      const float* Asrc = (ph == 0) ? hs : (ph == 1 ? h1d : h2d);
      float a00 = 0.f, a01 = 0.f, a10 = 0.f, a11 = 0.f, a20 = 0.f, a21 = 0.f;
      for (int ch = 0; ch < 4; ch++) {
        const float* src = Asrc + ch * 16384;
        for (int i = t * 4; i < 16384; i += 1024)
          *(float4*)(&HC[i]) = *(const float4*)(&src[i]);
        __syncthreads();
        const float* Wp = WL + ph * (3 * 4 * 512);
#pragma unroll 4
        for (int k4 = 0; k4 < 32; k4++) {
          const int kg = ch * 128 + k4 * 4;
          const float4 w0 = *(const float4*)(&Wp[(0 * 4 + cgp) * 512 + kg]);
          const float4 w1 = *(const float4*)(&Wp[(1 * 4 + cgp) * 512 + kg]);
          const float4 w2 = *(const float4*)(&Wp[(2 * 4 + cgp) * 512 + kg]);
          const float2 h0 = *(const float2*)(&HC[(k4 * 4 + 0) * 128 + rt * 2]);
          const float2 h1 = *(const float2*)(&HC[(k4 * 4 + 1) * 128 + rt * 2]);
          const float2 h2 = *(const float2*)(&HC[(k4 * 4 + 2) * 128 + rt * 2]);
          const float2 h3 = *(const float2*)(&HC[(k4 * 4 + 3) * 128 + rt * 2]);
          a00 = fmaf(h0.x, w0.x, fmaf(h1.x, w0.y, fmaf(h2.x, w0.z, fmaf(h3.x, w0.w, a00))));
          a01 = fmaf(h0.y, w0.x, fmaf(h1.y, w0.y, fmaf(h2.y, w0.z, fmaf(h3.y, w0.w, a01))));
          a10 = fmaf(h0.x, w1.x, fmaf(h1.x, w1.y, fmaf(h2.x, w1.z, fmaf(h3.x, w1.w, a10))));
          a11 = fmaf(h0.y, w1.x, fmaf(h1.y, w1.y, fmaf(h2.y, w1.z, fmaf(h3.y, w1.w, a11))));
          a20 = fmaf(h0.x, w2.x, fmaf(h1.x, w2.y, fmaf(h2.x, w2.z, fmaf(h3.x, w2.w, a20))));
          a21 = fmaf(h0.y, w2.x, fmaf(h1.y, w2.y, fmaf(h2.y, w2.z, fmaf(h3.y, w2.w, a21))));
        }
        __syncthreads();
      }
      // ---- fused gate combine ----
      if (ph == 0) {
        const size_t gb = (((size_t)dir * L_ + l) * G_) * B_;
        const float2 xz = *(const float2*)(&gxT[gb + (size_t)(j) * B_ + rt * 2]);
        const float2 xr = *(const float2*)(&gxT[gb + (size_t)(512 + j) * B_ + rt * 2]);
        const float2 xn = *(const float2*)(&gxT[gb + (size_t)(1024 + j) * B_ + rt * 2]);
        const float2 hp = *(const float2*)(&hs[(size_t)j * B_ + rt * 2]);
        hprev0 = hp.x; hprev1 = hp.y;
        {
          const float z = sigm(xz.x + a00);
          const float r = sigm(xr.x + a10);
          const float n = tanhf(xn.x + r * a20);
          hin0 = (1.0f - z) * hprev0 + z * n;
        }
        {
          const float z = sigm(xz.y + a01);
          const float r = sigm(xr.y + a11);
          const float n = tanhf(xn.y + r * a21);
          hin1 = (1.0f - z) * hprev1 + z * n;
        }
        float2 st; st.x = hin0; st.y = hin1;
        *(float2*)(&h1d[(size_t)j * B_ + rt * 2]) = st;
      } else {
        const float bz = tb[(ph - 1) * G_ + j];
        const float br = tb[(ph - 1) * G_ + 512 + j];
        const float bn = tb[(ph - 1) * G_ + 1024 + j];
        {
          const float z = sigm(a00 + bz);
          const float r = sigm(a10 + br);
          const float n = tanhf(r * (a20 + bn));
          hin0 = (1.0f - z) * hin0 + z * n;
        }
        {
          const float z = sigm(a01 + bz);
          const float r = sigm(a11 + br);
          const float n = tanhf(r * (a21 + bn));
          hin1 = (1.0f - z) * hin1 + z * n;
        }
        if (ph == 1) {
          float2 st; st.x = hin0; st.y = hin1;
          *(float2*)(&h2d[(size_t)j * B_ + rt * 2]) = st;
        } else {
          const float2 mv = *(const float2*)(&maskp[l * B_ + rt * 2]);
          const float hn0 = mv.x * hin0 + (1.0f - mv.x) * hprev0;
          const float hn1 = mv.y * hin1 + (1.0f - mv.y) * hprev1;
          float2 st; st.x = hn0; st.y = hn1;
          *(float2*)(&hs[(size_t)j * B_ + rt * 2]) = st;
          // out bounce via LDS for float4/lane stores
          HC[cgp * 128 + rt * 2]     = hn0 * mv.x;
          HC[cgp * 128 + rt * 2 + 1] = hn1 * mv.y;
          __syncthreads();
          if (t < B_) {
            float4 o;
            o.x = HC[0 * 128 + t];
            o.y = HC[1 * 128 + t];
            o.z = HC[2 * 128 + t];
            o.w = HC[3 * 128 + t];
            *(float4*)(&outp[((size_t)l * B_ + t) * 1024 + dir * 512 + J0]) = o;
          }
        }
      }
      __threadfence();
      grid.sync();
    }
  }
}

// ---------------------------------------------------------------------------
extern "C" void kernel_launch(void* const* d_in, const int* in_sizes, int n_in,
                              void* d_out, int out_size, void* d_ws, size_t ws_size,
                              hipStream_t stream) {
  const int*   xs   = (const int*)d_in[0];
  const float* mask = (const float*)d_in[1];
  const float* emb  = (const float*)d_in[2];
  const float* fWx  = (const float*)d_in[3];
  const float* fUh  = (const float*)d_in[4];
  const float* fb   = (const float*)d_in[5];
  const float* bWx  = (const float*)d_in[6];
  const float* bUh  = (const float*)d_in[7];
  const float* bb   = (const float*)d_in[8];
  const float* ftU  = (const float*)d_in[9];
  const float* ftb  = (const float*)d_in[10];
  const float* btU  = (const float*)d_in[11];
  const float* btb  = (const float*)d_in[12];
  float* out = (float*)d_out;

  // ws layout (floats): gxT[2][256][1536][128] | hstate[2][512][128] | htmp1 | htmp2
  // total = 404,226,048 bytes — assumed <= ws_size
  float* gxT    = (float*)d_ws;
  float* hstate = gxT + (size_t)2 * L_ * G_ * B_;
  float* htmp1  = hstate + (size_t)2 * H_ * B_;
  float* htmp2  = htmp1 + (size_t)2 * H_ * B_;

  dim3 gA(G_ / 128, L_, 2);
  gx_kernel<<<gA, 256, 0, stream>>>(xs, emb, fWx, fb, bWx, bb, gxT);

  void* args[] = { &gxT, &mask, &fUh, &bUh, &ftU, &btU, &ftb, &btb,
                   &hstate, &htmp1, &htmp2, &out };
  dim3 gR(256, 1, 1), bR(256, 1, 1);
  hipLaunchCooperativeKernel((void*)rec_kernel, gR, bR, args,
                             (unsigned int)(139264), stream);
}

// Round 3
// 16787.840 us; speedup vs baseline: 4.1504x; 4.1504x over previous
//
#include <hip/hip_runtime.h>
#include <math.h>

#define L_ 256
#define B_ 128
#define E_ 512
#define H_ 512
#define G_ 1536   // 3*H
#define NWG 256

__device__ __forceinline__ float sigm(float x) { return 1.0f / (1.0f + __expf(-x)); }

// ---------------------------------------------------------------------------
// Phase A: gxT[dir][l][col][b] = sum_k emb[xs[l][b]][k] * Wx[k][col] + bias[col]
// (unchanged — validated in round 1)
// ---------------------------------------------------------------------------
__global__ __launch_bounds__(256) void gx_kernel(
    const int* __restrict__ xs, const float* __restrict__ emb,
    const float* __restrict__ Wf, const float* __restrict__ bf,
    const float* __restrict__ Wb, const float* __restrict__ bbv,
    float* __restrict__ gxT)
{
  __shared__ float As[16 * 128];
  __shared__ float Bs[16 * 132];
  __shared__ int toks[B_];
  const int l = blockIdx.y;
  const int dir = blockIdx.z;
  const int col0 = blockIdx.x * 128;
  const float* __restrict__ Wx = dir ? Wb : Wf;
  const float* __restrict__ bias = dir ? bbv : bf;
  const int t = threadIdx.x;
  if (t < B_) toks[t] = xs[l * B_ + t];
  __syncthreads();
  const int ty = t >> 4, tx = t & 15;
  float acc[8][8];
#pragma unroll
  for (int i = 0; i < 8; i++)
#pragma unroll
    for (int j = 0; j < 8; j++) acc[i][j] = 0.0f;

  for (int k0 = 0; k0 < E_; k0 += 16) {
    {
      const int kk = t >> 4;
      const int cl = (t & 15) * 8;
      const float* src = Wx + (size_t)(k0 + kk) * G_ + col0 + cl;
      float4 v0 = *(const float4*)(src);
      float4 v1 = *(const float4*)(src + 4);
      *(float4*)(&As[kk * 128 + cl]) = v0;
      *(float4*)(&As[kk * 128 + cl + 4]) = v1;
    }
    {
      const int u = t & 15;
      const int v = t >> 4;
#pragma unroll
      for (int i = 0; i < 8; i++) {
        const int b = v * 8 + i;
        Bs[u * 132 + b] = emb[toks[b] * E_ + k0 + u];
      }
    }
    __syncthreads();
#pragma unroll
    for (int kk = 0; kk < 16; kk++) {
      float a[8], bv[8];
      *(float4*)(a)     = *(const float4*)(&As[kk * 128 + ty * 8]);
      *(float4*)(a + 4) = *(const float4*)(&As[kk * 128 + ty * 8 + 4]);
      *(float4*)(bv)     = *(const float4*)(&Bs[kk * 132 + tx * 8]);
      *(float4*)(bv + 4) = *(const float4*)(&Bs[kk * 132 + tx * 8 + 4]);
#pragma unroll
      for (int i = 0; i < 8; i++)
#pragma unroll
        for (int j = 0; j < 8; j++)
          acc[i][j] = fmaf(a[i], bv[j], acc[i][j]);
    }
    __syncthreads();
  }
  const size_t base = ((size_t)dir * L_ + l) * (size_t)G_ * B_;
#pragma unroll
  for (int i = 0; i < 8; i++) {
    const int col = col0 + ty * 8 + i;
    const float bvv = bias[col];
    float4 w0, w1;
    w0.x = acc[i][0] + bvv; w0.y = acc[i][1] + bvv; w0.z = acc[i][2] + bvv; w0.w = acc[i][3] + bvv;
    w1.x = acc[i][4] + bvv; w1.y = acc[i][5] + bvv; w1.z = acc[i][6] + bvv; w1.w = acc[i][7] + bvv;
    float* dst = gxT + base + (size_t)col * B_ + tx * 8;
    *(float4*)(dst)     = w0;
    *(float4*)(dst + 4) = w1;
  }
}

// ---------------------------------------------------------------------------
// Recurrence v3: persistent kernel, fence-correct custom barrier.
// 256 WGs x 256 thr, 1 WG/CU. WG -> (dir = wg&1, slc = wg>>1 -> 4 h-cols).
// Wave w owns k in [128w,128w+128); h chunks double-buffered IN REGISTERS
// (each lane consumes exactly the batch-pair it loads). Plain cached h
// loads/stores; coherence from explicit agent release/acquire fences in the
// barrier (every path, including the releasing WG — fixes round-2 bug).
// Two independent barrier domains (one per direction).
// ---------------------------------------------------------------------------

#define LOADC(BUF, C)                                                          \
  do {                                                                         \
    _Pragma("unroll") for (int it = 0; it < 16; ++it)                          \
        BUF[it] = s2[((C) * 16 + it) * 64];                                    \
  } while (0)

#define COMPUTE(BUF, C)                                                        \
  do {                                                                         \
    _Pragma("unroll") for (int k4 = 0; k4 < 4; ++k4) {                         \
      const int ko = kbase + (C) * 16 + k4 * 4;                                \
      const float2 hv0 = BUF[k4 * 4 + 0];                                      \
      const float2 hv1 = BUF[k4 * 4 + 1];                                      \
      const float2 hv2 = BUF[k4 * 4 + 2];                                      \
      const float2 hv3 = BUF[k4 * 4 + 3];                                      \
      _Pragma("unroll") for (int g = 0; g < 3; ++g) {                          \
        _Pragma("unroll") for (int cv = 0; cv < 4; ++cv) {                     \
          const float4 wv =                                                    \
              *(const float4*)&WL[(size_t)((ph * 3 + g) * 4 + cv) * 512 + ko]; \
          acc[g][cv][0] = fmaf(hv0.x, wv.x, fmaf(hv1.x, wv.y,                  \
                           fmaf(hv2.x, wv.z, fmaf(hv3.x, wv.w, acc[g][cv][0]))));\
          acc[g][cv][1] = fmaf(hv0.y, wv.x, fmaf(hv1.y, wv.y,                  \
                           fmaf(hv2.y, wv.z, fmaf(hv3.y, wv.w, acc[g][cv][1]))));\
        }                                                                      \
      }                                                                        \
    }                                                                          \
  } while (0)

__global__ __launch_bounds__(256, 1) void rec_kernel(
    const float* __restrict__ gxT, const float* __restrict__ maskp,
    const float* __restrict__ Uhf, const float* __restrict__ Uhb,
    const float* __restrict__ tUf, const float* __restrict__ tUb,
    const float* __restrict__ tbf, const float* __restrict__ tbb,
    float* __restrict__ hstate, float* __restrict__ htmp1,
    float* __restrict__ htmp2, unsigned* __restrict__ barp,
    float* __restrict__ outp)
{
  extern __shared__ float sm[];
  float* WL   = sm;            // [3ph][3g][4c][512k] = 18432 floats
  float* SW   = sm + 18432;    // [4 waves][12][128] partials = 6144 floats
  float* OUTS = sm + 24576;    // [4][128] = 512 floats

  const int wg   = blockIdx.x;
  const int dir  = wg & 1;
  const int slc  = wg >> 1;       // 0..127
  const int J0   = slc * 4;
  const int t    = threadIdx.x;
  const int lane = t & 63;
  const int w    = t >> 6;
  const int kbase = w * 128;
  const int b0   = lane * 2;
  const int c2   = w;
  const int j    = J0 + c2;

  const float* __restrict__ Uh = dir ? Uhb : Uhf;
  const float* __restrict__ tU = dir ? tUb : tUf;
  const float* __restrict__ tb = dir ? tbb : tbf;

  // one-time W column-slice load into LDS (reused for all 256 steps)
  for (int i = t; i < 18432; i += 256) {
    const int k = i & 511;
    const int cid = i >> 9;            // ph*12 + g*4 + c
    const int c = cid & 3;
    const int g = (cid >> 2) % 3;
    const int ph = cid / 12;
    const int col = g * 512 + J0 + c;
    WL[i] = (ph == 0) ? Uh[(size_t)k * G_ + col]
                      : tU[((size_t)(ph - 1) * H_ + k) * G_ + col];
  }
  __syncthreads();

  float2* hs  = ((float2*)hstate) + (size_t)dir * 32768;   // [512 k][64 pairs]
  float2* h1d = ((float2*)htmp1)  + (size_t)dir * 32768;
  float2* h2d = ((float2*)htmp2)  + (size_t)dir * 32768;
  unsigned* bd = barp + dir * 256;     // per-direction barrier domain
  const int grp = slc >> 5;            // 4 groups of 32 WGs

  unsigned nbar = 0;
  float hprev0 = 0.f, hprev1 = 0.f, hin0 = 0.f, hin1 = 0.f;

  for (int step = 0; step < L_; ++step) {
    const int l = dir ? (L_ - 1 - step) : step;
    for (int ph = 0; ph < 3; ++ph) {
      const float2* hb = (ph == 0) ? hs : (ph == 1 ? h1d : h2d);
      const float2* __restrict__ s2 = hb + (size_t)kbase * 64 + lane;

      float acc[3][4][2];
#pragma unroll
      for (int g = 0; g < 3; ++g)
#pragma unroll
        for (int cv = 0; cv < 4; ++cv) { acc[g][cv][0] = 0.f; acc[g][cv][1] = 0.f; }

      // register double-buffered k-chunks (16 rows each), 1-deep prefetch
      float2 A0[16], A1[16];
      LOADC(A0, 0);
      LOADC(A1, 1);
      COMPUTE(A0, 0); LOADC(A0, 2);
      COMPUTE(A1, 1); LOADC(A1, 3);
      COMPUTE(A0, 2); LOADC(A0, 4);
      COMPUTE(A1, 3); LOADC(A1, 5);
      COMPUTE(A0, 4); LOADC(A0, 6);
      COMPUTE(A1, 5); LOADC(A1, 7);
      COMPUTE(A0, 6);
      COMPUTE(A1, 7);

      // partials -> LDS
#pragma unroll
      for (int g = 0; g < 3; ++g)
#pragma unroll
        for (int cv = 0; cv < 4; ++cv) {
          float2 p; p.x = acc[g][cv][0]; p.y = acc[g][cv][1];
          *(float2*)&SW[(size_t)(w * 12 + g * 4 + cv) * 128 + b0] = p;
        }
      __syncthreads();

      // cross-wave k-reduce for this thread's (j, b0..b0+1)
      float az0 = 0.f, az1 = 0.f, ar0 = 0.f, ar1 = 0.f, an0 = 0.f, an1 = 0.f;
#pragma unroll
      for (int w4 = 0; w4 < 4; ++w4) {
        const float2 pz = *(const float2*)&SW[(size_t)(w4 * 12 + 0 + c2) * 128 + b0];
        const float2 pr = *(const float2*)&SW[(size_t)(w4 * 12 + 4 + c2) * 128 + b0];
        const float2 pn = *(const float2*)&SW[(size_t)(w4 * 12 + 8 + c2) * 128 + b0];
        az0 += pz.x; az1 += pz.y; ar0 += pr.x; ar1 += pr.y; an0 += pn.x; an1 += pn.y;
      }

      if (ph == 0) {
        const size_t gb = (((size_t)dir * L_ + l) * G_) * B_;
        const float2 xz = *(const float2*)&gxT[gb + (size_t)j * B_ + b0];
        const float2 xr = *(const float2*)&gxT[gb + (size_t)(512 + j) * B_ + b0];
        const float2 xn = *(const float2*)&gxT[gb + (size_t)(1024 + j) * B_ + b0];
        const float2 hp = hs[(size_t)j * 64 + lane];
        hprev0 = hp.x; hprev1 = hp.y;
        {
          const float z = sigm(xz.x + az0);
          const float r = sigm(xr.x + ar0);
          const float n = tanhf(xn.x + r * an0);
          hin0 = (1.0f - z) * hprev0 + z * n;
        }
        {
          const float z = sigm(xz.y + az1);
          const float r = sigm(xr.y + ar1);
          const float n = tanhf(xn.y + r * an1);
          hin1 = (1.0f - z) * hprev1 + z * n;
        }
        float2 st; st.x = hin0; st.y = hin1;
        h1d[(size_t)j * 64 + lane] = st;
      } else {
        const float gbz = tb[(ph - 1) * G_ + j];
        const float gbr = tb[(ph - 1) * G_ + 512 + j];
        const float gbn = tb[(ph - 1) * G_ + 1024 + j];
        {
          const float z = sigm(az0 + gbz);
          const float r = sigm(ar0 + gbr);
          const float n = tanhf(r * (an0 + gbn));
          hin0 = (1.0f - z) * hin0 + z * n;
        }
        {
          const float z = sigm(az1 + gbz);
          const float r = sigm(ar1 + gbr);
          const float n = tanhf(r * (an1 + gbn));
          hin1 = (1.0f - z) * hin1 + z * n;
        }
        if (ph == 1) {
          float2 st; st.x = hin0; st.y = hin1;
          h2d[(size_t)j * 64 + lane] = st;
        } else {
          const float2 mv = *(const float2*)&maskp[l * B_ + b0];
          const float hn0 = mv.x * hin0 + (1.0f - mv.x) * hprev0;
          const float hn1 = mv.y * hin1 + (1.0f - mv.y) * hprev1;
          float2 st; st.x = hn0; st.y = hn1;
          hs[(size_t)j * 64 + lane] = st;
          OUTS[c2 * 128 + b0]     = hn0 * mv.x;
          OUTS[c2 * 128 + b0 + 1] = hn1 * mv.y;
          __syncthreads();
          if (t < B_) {
            float4 o;
            o.x = OUTS[0 * 128 + t];
            o.y = OUTS[1 * 128 + t];
            o.z = OUTS[2 * 128 + t];
            o.w = OUTS[3 * 128 + t];
            *(float4*)(&outp[((size_t)l * B_ + t) * 1024 + dir * 512 + J0]) = o;
          }
        }
      }

      // ---- per-direction global barrier, fence-correct on ALL paths ----
      nbar++;
      const bool isLast = (step == L_ - 1) && (ph == 2);
      if (!isLast) {
        __syncthreads();   // all WG stores issued & vmcnt-drained
        if (t == 0) {
          // release: write back this XCD's dirty L2 lines to MALL, wait
          __builtin_amdgcn_fence(__ATOMIC_RELEASE, "agent");
          const unsigned r = __hip_atomic_fetch_add(&bd[32 * (1 + grp)], 1u,
                                                    __ATOMIC_RELAXED, __HIP_MEMORY_SCOPE_AGENT);
          if (r == nbar * 32 - 1) {
            const unsigned rr = __hip_atomic_fetch_add(&bd[0], 1u,
                                                       __ATOMIC_RELAXED, __HIP_MEMORY_SCOPE_AGENT);
            if (rr == nbar * 4 - 1)
              __hip_atomic_store(&bd[192], nbar, __ATOMIC_RELAXED, __HIP_MEMORY_SCOPE_AGENT);
          }
          while (__hip_atomic_load(&bd[192], __ATOMIC_RELAXED, __HIP_MEMORY_SCOPE_AGENT) < nbar)
            __builtin_amdgcn_s_sleep(1);
          // acquire: invalidate L1 + this XCD's L2 so plain loads refetch
          __builtin_amdgcn_fence(__ATOMIC_ACQUIRE, "agent");
        }
        __syncthreads();
      }
    }
  }
}

// ---------------------------------------------------------------------------
extern "C" void kernel_launch(void* const* d_in, const int* in_sizes, int n_in,
                              void* d_out, int out_size, void* d_ws, size_t ws_size,
                              hipStream_t stream) {
  const int*   xs   = (const int*)d_in[0];
  const float* mask = (const float*)d_in[1];
  const float* emb  = (const float*)d_in[2];
  const float* fWx  = (const float*)d_in[3];
  const float* fUh  = (const float*)d_in[4];
  const float* fb   = (const float*)d_in[5];
  const float* bWx  = (const float*)d_in[6];
  const float* bUh  = (const float*)d_in[7];
  const float* bb   = (const float*)d_in[8];
  const float* ftU  = (const float*)d_in[9];
  const float* ftb  = (const float*)d_in[10];
  const float* btU  = (const float*)d_in[11];
  const float* btb  = (const float*)d_in[12];
  float* out = (float*)d_out;

  // ws: gxT[2][256][1536][128] f32 | hstate | htmp1 | htmp2 | barrier words
  float* gxT    = (float*)d_ws;
  float* hstate = gxT + (size_t)2 * L_ * G_ * B_;
  float* htmp1  = hstate + (size_t)2 * H_ * B_;
  float* htmp2  = htmp1 + (size_t)2 * H_ * B_;
  unsigned* barp = (unsigned*)(htmp2 + (size_t)2 * H_ * B_);

  // zero h state + barrier words each launch (replay-safe)
  hipMemsetAsync(hstate, 0, (size_t)3 * 2 * H_ * B_ * sizeof(float) + 2048, stream);

  dim3 gA(G_ / 128, L_, 2);
  gx_kernel<<<gA, 256, 0, stream>>>(xs, emb, fWx, fb, bWx, bb, gxT);

  void* args[] = { &gxT, &mask, &fUh, &bUh, &ftU, &btU, &ftb, &btb,
                   &hstate, &htmp1, &htmp2, &barp, &out };
  dim3 gR(NWG, 1, 1), bR(256, 1, 1);
  hipLaunchCooperativeKernel((void*)rec_kernel, gR, bR, args, 100352u, stream);
}

// Round 8
// 13236.798 us; speedup vs baseline: 5.2638x; 1.2683x over previous
//
#include <hip/hip_runtime.h>
#include <math.h>

#define L_ 256
#define B_ 128
#define E_ 512
#define H_ 512
#define G_ 1536   // 3*H

__device__ __forceinline__ float sigm(float x) { return 1.0f / (1.0f + __expf(-x)); }

// ---------------------------------------------------------------------------
// Phase A: gxT[dir][l][col][b] = sum_k emb[xs[l][b]][k] * Wx[k][col] + bias[col]
// (unchanged — validated in rounds 1/3)
// ---------------------------------------------------------------------------
__global__ __launch_bounds__(256) void gx_kernel(
    const int* __restrict__ xs, const float* __restrict__ emb,
    const float* __restrict__ Wf, const float* __restrict__ bf,
    const float* __restrict__ Wb, const float* __restrict__ bbv,
    float* __restrict__ gxT)
{
  __shared__ float As[16 * 128];
  __shared__ float Bs[16 * 132];
  __shared__ int toks[B_];
  const int l = blockIdx.y;
  const int dir = blockIdx.z;
  const int col0 = blockIdx.x * 128;
  const float* __restrict__ Wx = dir ? Wb : Wf;
  const float* __restrict__ bias = dir ? bbv : bf;
  const int t = threadIdx.x;
  if (t < B_) toks[t] = xs[l * B_ + t];
  __syncthreads();
  const int ty = t >> 4, tx = t & 15;
  float acc[8][8];
#pragma unroll
  for (int i = 0; i < 8; i++)
#pragma unroll
    for (int j = 0; j < 8; j++) acc[i][j] = 0.0f;

  for (int k0 = 0; k0 < E_; k0 += 16) {
    {
      const int kk = t >> 4;
      const int cl = (t & 15) * 8;
      const float* src = Wx + (size_t)(k0 + kk) * G_ + col0 + cl;
      float4 v0 = *(const float4*)(src);
      float4 v1 = *(const float4*)(src + 4);
      *(float4*)(&As[kk * 128 + cl]) = v0;
      *(float4*)(&As[kk * 128 + cl + 4]) = v1;
    }
    {
      const int u = t & 15;
      const int v = t >> 4;
#pragma unroll
      for (int i = 0; i < 8; i++) {
        const int b = v * 8 + i;
        Bs[u * 132 + b] = emb[toks[b] * E_ + k0 + u];
      }
    }
    __syncthreads();
#pragma unroll
    for (int kk = 0; kk < 16; kk++) {
      float a[8], bv[8];
      *(float4*)(a)     = *(const float4*)(&As[kk * 128 + ty * 8]);
      *(float4*)(a + 4) = *(const float4*)(&As[kk * 128 + ty * 8 + 4]);
      *(float4*)(bv)     = *(const float4*)(&Bs[kk * 132 + tx * 8]);
      *(float4*)(bv + 4) = *(const float4*)(&Bs[kk * 132 + tx * 8 + 4]);
#pragma unroll
      for (int i = 0; i < 8; i++)
#pragma unroll
        for (int j = 0; j < 8; j++)
          acc[i][j] = fmaf(a[i], bv[j], acc[i][j]);
    }
    __syncthreads();
  }
  const size_t base = ((size_t)dir * L_ + l) * (size_t)G_ * B_;
#pragma unroll
  for (int i = 0; i < 8; i++) {
    const int col = col0 + ty * 8 + i;
    const float bvv = bias[col];
    float4 w0, w1;
    w0.x = acc[i][0] + bvv; w0.y = acc[i][1] + bvv; w0.z = acc[i][2] + bvv; w0.w = acc[i][3] + bvv;
    w1.x = acc[i][4] + bvv; w1.y = acc[i][5] + bvv; w1.z = acc[i][6] + bvv; w1.w = acc[i][7] + bvv;
    float* dst = gxT + base + (size_t)col * B_ + tx * 8;
    *(float4*)(dst)     = w0;
    *(float4*)(dst + 4) = w1;
  }
}

// ---------------------------------------------------------------------------
// Recurrence v8: ONE LAUNCH PER PHASE (768 launches). No cooperative launch,
// no custom barrier, no fences, no atomics — cross-WG visibility comes from
// kernel dispatch boundaries (runtime handles XCD L2 release/acquire once
// per XCD, not 32x in software like R3's fences).
// 256 WGs x 256 thr: wg -> (dir = wg&1, slc = wg>>1 -> h-cols J0..J0+3).
// Wave w owns k in [128w,128w+128); h streamed via R3's validated 16-row
// register double-buffer; per-launch weight slice staged LDS-side from
// Uh/tU directly (float4 gathers, L2-resident).
// Buffers: ph0: hs->h1, ph1: h1->h2, ph2: h2->hs (hprev read = own elem).
// ---------------------------------------------------------------------------

#define LOADC(BUF, C)                                                          \
  do {                                                                         \
    _Pragma("unroll") for (int it = 0; it < 16; ++it)                          \
        BUF[it] = s2[((C) * 16 + it) * 64];                                    \
  } while (0)

#define COMPUTE(BUF, C)                                                        \
  do {                                                                         \
    _Pragma("unroll") for (int k4 = 0; k4 < 4; ++k4) {                         \
      const int ko = kbase + (C) * 16 + k4 * 4;                                \
      const float2 hv0 = BUF[k4 * 4 + 0];                                      \
      const float2 hv1 = BUF[k4 * 4 + 1];                                      \
      const float2 hv2 = BUF[k4 * 4 + 2];                                      \
      const float2 hv3 = BUF[k4 * 4 + 3];                                      \
      _Pragma("unroll") for (int g = 0; g < 3; ++g) {                          \
        _Pragma("unroll") for (int cv = 0; cv < 4; ++cv) {                     \
          const float4 wv =                                                    \
              *(const float4*)&WL[(size_t)(g * 4 + cv) * 512 + ko];            \
          acc[g][cv][0] = fmaf(hv0.x, wv.x, fmaf(hv1.x, wv.y,                  \
                           fmaf(hv2.x, wv.z, fmaf(hv3.x, wv.w, acc[g][cv][0]))));\
          acc[g][cv][1] = fmaf(hv0.y, wv.x, fmaf(hv1.y, wv.y,                  \
                           fmaf(hv2.y, wv.z, fmaf(hv3.y, wv.w, acc[g][cv][1]))));\
        }                                                                      \
      }                                                                        \
    }                                                                          \
  } while (0)

__global__ __launch_bounds__(256) void rec_phase(
    const float* __restrict__ gxT, const float* __restrict__ maskp,
    const float* __restrict__ Uhf, const float* __restrict__ Uhb,
    const float* __restrict__ tUf, const float* __restrict__ tUb,
    const float* __restrict__ tbf, const float* __restrict__ tbb,
    const float* hin, float* hout, const float* hsp,
    float* __restrict__ outp, int step, int ph)
{
  __shared__ float WL[12 * 512];   // [g*4+c][k] current phase's 12 gate-cols
  __shared__ float SW[4 * 12 * 128];
  __shared__ float OUTS[4 * 128];

  const int wg   = blockIdx.x;
  const int dir  = wg & 1;
  const int slc  = wg >> 1;       // 0..127
  const int J0   = slc * 4;
  const int t    = threadIdx.x;
  const int lane = t & 63;
  const int w    = t >> 6;
  const int kbase = w * 128;
  const int b0   = lane * 2;
  const int c2   = w;
  const int j    = J0 + c2;
  const int l    = dir ? (L_ - 1 - step) : step;

  // stage this phase's weight slice: U[k][g*512 + J0 .. J0+3] -> WL[g*4+c][k]
  const float* U = (ph == 0) ? (dir ? Uhb : Uhf)
                             : ((dir ? tUb : tUf) + (size_t)(ph - 1) * H_ * G_);
  for (int i = t; i < 1536; i += 256) {
    const int g = i >> 9;            // 0..2
    const int k = i & 511;
    const float4 v = *(const float4*)&U[(size_t)k * G_ + g * 512 + J0];
    WL[(g * 4 + 0) * 512 + k] = v.x;
    WL[(g * 4 + 1) * 512 + k] = v.y;
    WL[(g * 4 + 2) * 512 + k] = v.z;
    WL[(g * 4 + 3) * 512 + k] = v.w;
  }
  __syncthreads();

  const float2* hin2 = ((const float2*)hin) + (size_t)dir * 32768;  // [512][64]
  float2*       hout2 = ((float2*)hout)     + (size_t)dir * 32768;
  const float2* hs2  = ((const float2*)hsp) + (size_t)dir * 32768;
  const float2* s2 = hin2 + (size_t)kbase * 64 + lane;

  float acc[3][4][2];
#pragma unroll
  for (int g = 0; g < 3; ++g)
#pragma unroll
    for (int cv = 0; cv < 4; ++cv) { acc[g][cv][0] = 0.f; acc[g][cv][1] = 0.f; }

  // register double-buffered k-chunks (16 rows each), 1-deep prefetch (R3)
  float2 A0[16], A1[16];
  LOADC(A0, 0);
  LOADC(A1, 1);
  COMPUTE(A0, 0); LOADC(A0, 2);
  COMPUTE(A1, 1); LOADC(A1, 3);
  COMPUTE(A0, 2); LOADC(A0, 4);
  COMPUTE(A1, 3); LOADC(A1, 5);
  COMPUTE(A0, 4); LOADC(A0, 6);
  COMPUTE(A1, 5); LOADC(A1, 7);
  COMPUTE(A0, 6);
  COMPUTE(A1, 7);

  // partials -> LDS
#pragma unroll
  for (int g = 0; g < 3; ++g)
#pragma unroll
    for (int cv = 0; cv < 4; ++cv) {
      float2 p; p.x = acc[g][cv][0]; p.y = acc[g][cv][1];
      *(float2*)&SW[(size_t)(w * 12 + g * 4 + cv) * 128 + b0] = p;
    }
  __syncthreads();

  // cross-wave k-reduce for this thread's (j, b0..b0+1)
  float az0 = 0.f, az1 = 0.f, ar0 = 0.f, ar1 = 0.f, an0 = 0.f, an1 = 0.f;
#pragma unroll
  for (int w4 = 0; w4 < 4; ++w4) {
    const float2 pz = *(const float2*)&SW[(size_t)(w4 * 12 + 0 + c2) * 128 + b0];
    const float2 pr = *(const float2*)&SW[(size_t)(w4 * 12 + 4 + c2) * 128 + b0];
    const float2 pn = *(const float2*)&SW[(size_t)(w4 * 12 + 8 + c2) * 128 + b0];
    az0 += pz.x; az1 += pz.y; ar0 += pr.x; ar1 += pr.y; an0 += pn.x; an1 += pn.y;
  }

  if (ph == 0) {
    const size_t gb = (((size_t)dir * L_ + l) * G_) * B_;
    const float2 xz = *(const float2*)&gxT[gb + (size_t)j * B_ + b0];
    const float2 xr = *(const float2*)&gxT[gb + (size_t)(512 + j) * B_ + b0];
    const float2 xn = *(const float2*)&gxT[gb + (size_t)(1024 + j) * B_ + b0];
    const float2 hp = hin2[(size_t)j * 64 + lane];   // h_{t-1} own element
    float2 st;
    {
      const float z = sigm(xz.x + az0);
      const float r = sigm(xr.x + ar0);
      const float n = tanhf(xn.x + r * an0);
      st.x = (1.0f - z) * hp.x + z * n;
    }
    {
      const float z = sigm(xz.y + az1);
      const float r = sigm(xr.y + ar1);
      const float n = tanhf(xn.y + r * an1);
      st.y = (1.0f - z) * hp.y + z * n;
    }
    hout2[(size_t)j * 64 + lane] = st;
  } else if (ph == 1) {
    const float* tb = dir ? tbb : tbf;
    const float bz = tb[j], br = tb[512 + j], bn = tb[1024 + j];
    const float2 hc = hin2[(size_t)j * 64 + lane];   // h1 own element
    float2 st;
    {
      const float z = sigm(az0 + bz);
      const float r = sigm(ar0 + br);
      const float n = tanhf(r * (an0 + bn));
      st.x = (1.0f - z) * hc.x + z * n;
    }
    {
      const float z = sigm(az1 + bz);
      const float r = sigm(ar1 + br);
      const float n = tanhf(r * (an1 + bn));
      st.y = (1.0f - z) * hc.y + z * n;
    }
    hout2[(size_t)j * 64 + lane] = st;
  } else {
    const float* tb = dir ? tbb : tbf;
    const float bz = tb[G_ + j], br = tb[G_ + 512 + j], bn = tb[G_ + 1024 + j];
    const float2 hc = hin2[(size_t)j * 64 + lane];   // h2 own element
    const float2 hp = hs2[(size_t)j * 64 + lane];    // h_{t-1} own element
    const float2 mv = *(const float2*)&maskp[l * B_ + b0];
    float hin0, hin1;
    {
      const float z = sigm(az0 + bz);
      const float r = sigm(ar0 + br);
      const float n = tanhf(r * (an0 + bn));
      hin0 = (1.0f - z) * hc.x + z * n;
    }
    {
      const float z = sigm(az1 + bz);
      const float r = sigm(ar1 + br);
      const float n = tanhf(r * (an1 + bn));
      hin1 = (1.0f - z) * hc.y + z * n;
    }
    const float hn0 = mv.x * hin0 + (1.0f - mv.x) * hp.x;
    const float hn1 = mv.y * hin1 + (1.0f - mv.y) * hp.y;
    float2 st; st.x = hn0; st.y = hn1;
    hout2[(size_t)j * 64 + lane] = st;               // hout == hstate
    OUTS[c2 * 128 + b0]     = hn0 * mv.x;
    OUTS[c2 * 128 + b0 + 1] = hn1 * mv.y;
    __syncthreads();
    if (t < B_) {
      float4 o;
      o.x = OUTS[0 * 128 + t];
      o.y = OUTS[1 * 128 + t];
      o.z = OUTS[2 * 128 + t];
      o.w = OUTS[3 * 128 + t];
      *(float4*)(&outp[((size_t)l * B_ + t) * 1024 + dir * 512 + J0]) = o;
    }
  }
}

// ---------------------------------------------------------------------------
extern "C" void kernel_launch(void* const* d_in, const int* in_sizes, int n_in,
                              void* d_out, int out_size, void* d_ws, size_t ws_size,
                              hipStream_t stream) {
  const int*   xs   = (const int*)d_in[0];
  const float* mask = (const float*)d_in[1];
  const float* emb  = (const float*)d_in[2];
  const float* fWx  = (const float*)d_in[3];
  const float* fUh  = (const float*)d_in[4];
  const float* fb   = (const float*)d_in[5];
  const float* bWx  = (const float*)d_in[6];
  const float* bUh  = (const float*)d_in[7];
  const float* bb   = (const float*)d_in[8];
  const float* ftU  = (const float*)d_in[9];
  const float* ftb  = (const float*)d_in[10];
  const float* btU  = (const float*)d_in[11];
  const float* btb  = (const float*)d_in[12];
  float* out = (float*)d_out;

  // ws: gxT[2][256][1536][128] f32 | hstate | htmp1 | htmp2  (404 MB total,
  // within the footprint proven in rounds 1/3)
  float* gxT    = (float*)d_ws;
  float* hstate = gxT + (size_t)2 * L_ * G_ * B_;
  float* htmp1  = hstate + (size_t)2 * H_ * B_;
  float* htmp2  = htmp1 + (size_t)2 * H_ * B_;

  // zero initial h (replay-safe)
  hipMemsetAsync(hstate, 0, (size_t)2 * H_ * B_ * sizeof(float), stream);

  dim3 gA(G_ / 128, L_, 2);
  gx_kernel<<<gA, 256, 0, stream>>>(xs, emb, fWx, fb, bWx, bb, gxT);

  for (int step = 0; step < L_; ++step) {
    rec_phase<<<256, 256, 0, stream>>>(gxT, mask, fUh, bUh, ftU, btU, ftb, btb,
                                       hstate, htmp1, hstate, out, step, 0);
    rec_phase<<<256, 256, 0, stream>>>(gxT, mask, fUh, bUh, ftU, btU, ftb, btb,
                                       htmp1, htmp2, hstate, out, step, 1);
    rec_phase<<<256, 256, 0, stream>>>(gxT, mask, fUh, bUh, ftU, btU, ftb, btb,
                                       htmp2, hstate, hstate, out, step, 2);
  }
}

// Round 9
// 11079.431 us; speedup vs baseline: 6.2888x; 1.1947x over previous
//
#include <hip/hip_runtime.h>
#include <math.h>

#define L_ 256
#define B_ 128
#define E_ 512
#define H_ 512
#define G_ 1536   // 3*H

__device__ __forceinline__ float sigm(float x) { return 1.0f / (1.0f + __expf(-x)); }

// ---------------------------------------------------------------------------
// Phase A: gxT[dir][l][col][b] = sum_k emb[xs[l][b]][k] * Wx[k][col] + bias[col]
// (unchanged — validated in rounds 1/3/8)
// ---------------------------------------------------------------------------
__global__ __launch_bounds__(256) void gx_kernel(
    const int* __restrict__ xs, const float* __restrict__ emb,
    const float* __restrict__ Wf, const float* __restrict__ bf,
    const float* __restrict__ Wb, const float* __restrict__ bbv,
    float* __restrict__ gxT)
{
  __shared__ float As[16 * 128];
  __shared__ float Bs[16 * 132];
  __shared__ int toks[B_];
  const int l = blockIdx.y;
  const int dir = blockIdx.z;
  const int col0 = blockIdx.x * 128;
  const float* __restrict__ Wx = dir ? Wb : Wf;
  const float* __restrict__ bias = dir ? bbv : bf;
  const int t = threadIdx.x;
  if (t < B_) toks[t] = xs[l * B_ + t];
  __syncthreads();
  const int ty = t >> 4, tx = t & 15;
  float acc[8][8];
#pragma unroll
  for (int i = 0; i < 8; i++)
#pragma unroll
    for (int j = 0; j < 8; j++) acc[i][j] = 0.0f;

  for (int k0 = 0; k0 < E_; k0 += 16) {
    {
      const int kk = t >> 4;
      const int cl = (t & 15) * 8;
      const float* src = Wx + (size_t)(k0 + kk) * G_ + col0 + cl;
      float4 v0 = *(const float4*)(src);
      float4 v1 = *(const float4*)(src + 4);
      *(float4*)(&As[kk * 128 + cl]) = v0;
      *(float4*)(&As[kk * 128 + cl + 4]) = v1;
    }
    {
      const int u = t & 15;
      const int v = t >> 4;
#pragma unroll
      for (int i = 0; i < 8; i++) {
        const int b = v * 8 + i;
        Bs[u * 132 + b] = emb[toks[b] * E_ + k0 + u];
      }
    }
    __syncthreads();
#pragma unroll
    for (int kk = 0; kk < 16; kk++) {
      float a[8], bv[8];
      *(float4*)(a)     = *(const float4*)(&As[kk * 128 + ty * 8]);
      *(float4*)(a + 4) = *(const float4*)(&As[kk * 128 + ty * 8 + 4]);
      *(float4*)(bv)     = *(const float4*)(&Bs[kk * 132 + tx * 8]);
      *(float4*)(bv + 4) = *(const float4*)(&Bs[kk * 132 + tx * 8 + 4]);
#pragma unroll
      for (int i = 0; i < 8; i++)
#pragma unroll
        for (int j = 0; j < 8; j++)
          acc[i][j] = fmaf(a[i], bv[j], acc[i][j]);
    }
    __syncthreads();
  }
  const size_t base = ((size_t)dir * L_ + l) * (size_t)G_ * B_;
#pragma unroll
  for (int i = 0; i < 8; i++) {
    const int col = col0 + ty * 8 + i;
    const float bvv = bias[col];
    float4 w0, w1;
    w0.x = acc[i][0] + bvv; w0.y = acc[i][1] + bvv; w0.z = acc[i][2] + bvv; w0.w = acc[i][3] + bvv;
    w1.x = acc[i][4] + bvv; w1.y = acc[i][5] + bvv; w1.z = acc[i][6] + bvv; w1.w = acc[i][7] + bvv;
    float* dst = gxT + base + (size_t)col * B_ + tx * 8;
    *(float4*)(dst)     = w0;
    *(float4*)(dst + 4) = w1;
  }
}

// ---------------------------------------------------------------------------
// One-time weight pre-transpose: wp[dir][ph][slc][g*4+c][k]  (24 KB slices,
// contiguous per (dir,ph,slc)) — pays the strided gather ONCE instead of 768x.
// ---------------------------------------------------------------------------
__global__ __launch_bounds__(256) void wprep_kernel(
    const float* __restrict__ Uhf, const float* __restrict__ Uhb,
    const float* __restrict__ tUf, const float* __restrict__ tUb,
    float* __restrict__ wp)
{
  const int slc = blockIdx.x;        // 0..127
  const int ph  = blockIdx.y;        // 0..2
  const int dir = blockIdx.z;        // 0..1
  const int J0  = slc * 4;
  const int t   = threadIdx.x;
  const float* U = (ph == 0) ? (dir ? Uhb : Uhf)
                             : ((dir ? tUb : tUf) + (size_t)(ph - 1) * H_ * G_);
  float* dst = wp + (size_t)((dir * 3 + ph) * 128 + slc) * 6144;
  for (int i = t; i < 1536; i += 256) {
    const int g = i >> 9;            // 0..2
    const int k = i & 511;
    const float4 v = *(const float4*)&U[(size_t)k * G_ + g * 512 + J0];
    dst[(g * 4 + 0) * 512 + k] = v.x;
    dst[(g * 4 + 1) * 512 + k] = v.y;
    dst[(g * 4 + 2) * 512 + k] = v.z;
    dst[(g * 4 + 3) * 512 + k] = v.w;
  }
}

// ---------------------------------------------------------------------------
// Recurrence v9: ONE LAUNCH PER PHASE (768 launches) — passing R8 skeleton,
// with (a) coalesced weight staging from pre-transposed wp (fallback to the
// R8 strided gather if wp == nullptr), (b) h-load prologue + gate-input loads
// issued BEFORE the LDS stage so cold-miss latency hides under staging.
// 256 WGs x 256 thr: wg -> (dir = wg&1, slc = wg>>1 -> h-cols J0..J0+3).
// Buffers: ph0: hs->h1, ph1: h1->h2, ph2: h2->hs.
// ---------------------------------------------------------------------------

#define LOADC(BUF, C)                                                          \
  do {                                                                         \
    _Pragma("unroll") for (int it = 0; it < 16; ++it)                          \
        BUF[it] = s2[((C) * 16 + it) * 64];                                    \
  } while (0)

#define COMPUTE(BUF, C)                                                        \
  do {                                                                         \
    _Pragma("unroll") for (int k4 = 0; k4 < 4; ++k4) {                         \
      const int ko = kbase + (C) * 16 + k4 * 4;                                \
      const float2 hv0 = BUF[k4 * 4 + 0];                                      \
      const float2 hv1 = BUF[k4 * 4 + 1];                                      \
      const float2 hv2 = BUF[k4 * 4 + 2];                                      \
      const float2 hv3 = BUF[k4 * 4 + 3];                                      \
      _Pragma("unroll") for (int g = 0; g < 3; ++g) {                          \
        _Pragma("unroll") for (int cv = 0; cv < 4; ++cv) {                     \
          const float4 wv =                                                    \
              *(const float4*)&WL[(size_t)(g * 4 + cv) * 512 + ko];            \
          acc[g][cv][0] = fmaf(hv0.x, wv.x, fmaf(hv1.x, wv.y,                  \
                           fmaf(hv2.x, wv.z, fmaf(hv3.x, wv.w, acc[g][cv][0]))));\
          acc[g][cv][1] = fmaf(hv0.y, wv.x, fmaf(hv1.y, wv.y,                  \
                           fmaf(hv2.y, wv.z, fmaf(hv3.y, wv.w, acc[g][cv][1]))));\
        }                                                                      \
      }                                                                        \
    }                                                                          \
  } while (0)

__global__ __launch_bounds__(256) void rec_phase(
    const float* __restrict__ gxT, const float* __restrict__ maskp,
    const float* __restrict__ Uhf, const float* __restrict__ Uhb,
    const float* __restrict__ tUf, const float* __restrict__ tUb,
    const float* __restrict__ tbf, const float* __restrict__ tbb,
    const float* hin, float* hout, const float* hsp,
    const float* __restrict__ wp,
    float* __restrict__ outp, int step, int ph)
{
  __shared__ float WL[12 * 512];   // [g*4+c][k] current phase's 12 gate-cols
  __shared__ float SW[4 * 12 * 128];
  __shared__ float OUTS[4 * 128];

  const int wg   = blockIdx.x;
  const int dir  = wg & 1;
  const int slc  = wg >> 1;       // 0..127
  const int J0   = slc * 4;
  const int t    = threadIdx.x;
  const int lane = t & 63;
  const int w    = t >> 6;
  const int kbase = w * 128;
  const int b0   = lane * 2;
  const int c2   = w;
  const int j    = J0 + c2;
  const int l    = dir ? (L_ - 1 - step) : step;

  const float2* hin2 = ((const float2*)hin) + (size_t)dir * 32768;  // [512][64]
  float2*       hout2 = ((float2*)hout)     + (size_t)dir * 32768;
  const float2* hs2  = ((const float2*)hsp) + (size_t)dir * 32768;
  const float2* s2 = hin2 + (size_t)kbase * 64 + lane;

  // ---- issue h prologue + gate-input loads FIRST (hide latency under stage)
  float2 A0[16], A1[16];
  LOADC(A0, 0);
  LOADC(A1, 1);

  float2 xz, xr, xn, mv, hc, hp;
  xz.x = xz.y = xr.x = xr.y = xn.x = xn.y = 0.f;
  mv.x = mv.y = 0.f; hc.x = hc.y = 0.f; hp.x = hp.y = 0.f;
  if (ph == 0) {
    const size_t gb = (((size_t)dir * L_ + l) * G_) * B_;
    xz = *(const float2*)&gxT[gb + (size_t)j * B_ + b0];
    xr = *(const float2*)&gxT[gb + (size_t)(512 + j) * B_ + b0];
    xn = *(const float2*)&gxT[gb + (size_t)(1024 + j) * B_ + b0];
    hp = hin2[(size_t)j * 64 + lane];
  } else if (ph == 1) {
    hc = hin2[(size_t)j * 64 + lane];
  } else {
    hc = hin2[(size_t)j * 64 + lane];
    hp = hs2[(size_t)j * 64 + lane];
    mv = *(const float2*)&maskp[l * B_ + b0];
  }

  // ---- stage this phase's weight slice into LDS
  if (wp != nullptr) {
    // coalesced: contiguous 24 KB slice
    const float* slice = wp + (size_t)((dir * 3 + ph) * 128 + slc) * 6144;
    for (int i = t * 4; i < 6144; i += 1024)
      *(float4*)&WL[i] = *(const float4*)&slice[i];
  } else {
    // fallback: R8 strided gather
    const float* U = (ph == 0) ? (dir ? Uhb : Uhf)
                               : ((dir ? tUb : tUf) + (size_t)(ph - 1) * H_ * G_);
    for (int i = t; i < 1536; i += 256) {
      const int g = i >> 9;
      const int k = i & 511;
      const float4 v = *(const float4*)&U[(size_t)k * G_ + g * 512 + J0];
      WL[(g * 4 + 0) * 512 + k] = v.x;
      WL[(g * 4 + 1) * 512 + k] = v.y;
      WL[(g * 4 + 2) * 512 + k] = v.z;
      WL[(g * 4 + 3) * 512 + k] = v.w;
    }
  }
  __syncthreads();

  float acc[3][4][2];
#pragma unroll
  for (int g = 0; g < 3; ++g)
#pragma unroll
    for (int cv = 0; cv < 4; ++cv) { acc[g][cv][0] = 0.f; acc[g][cv][1] = 0.f; }

  // register double-buffered k-chunks (16 rows each), 1-deep prefetch
  COMPUTE(A0, 0); LOADC(A0, 2);
  COMPUTE(A1, 1); LOADC(A1, 3);
  COMPUTE(A0, 2); LOADC(A0, 4);
  COMPUTE(A1, 3); LOADC(A1, 5);
  COMPUTE(A0, 4); LOADC(A0, 6);
  COMPUTE(A1, 5); LOADC(A1, 7);
  COMPUTE(A0, 6);
  COMPUTE(A1, 7);

  // partials -> LDS
#pragma unroll
  for (int g = 0; g < 3; ++g)
#pragma unroll
    for (int cv = 0; cv < 4; ++cv) {
      float2 p; p.x = acc[g][cv][0]; p.y = acc[g][cv][1];
      *(float2*)&SW[(size_t)(w * 12 + g * 4 + cv) * 128 + b0] = p;
    }
  __syncthreads();

  // cross-wave k-reduce for this thread's (j, b0..b0+1)
  float az0 = 0.f, az1 = 0.f, ar0 = 0.f, ar1 = 0.f, an0 = 0.f, an1 = 0.f;
#pragma unroll
  for (int w4 = 0; w4 < 4; ++w4) {
    const float2 pz = *(const float2*)&SW[(size_t)(w4 * 12 + 0 + c2) * 128 + b0];
    const float2 pr = *(const float2*)&SW[(size_t)(w4 * 12 + 4 + c2) * 128 + b0];
    const float2 pn = *(const float2*)&SW[(size_t)(w4 * 12 + 8 + c2) * 128 + b0];
    az0 += pz.x; az1 += pz.y; ar0 += pr.x; ar1 += pr.y; an0 += pn.x; an1 += pn.y;
  }

  if (ph == 0) {
    float2 st;
    {
      const float z = sigm(xz.x + az0);
      const float r = sigm(xr.x + ar0);
      const float n = tanhf(xn.x + r * an0);
      st.x = (1.0f - z) * hp.x + z * n;
    }
    {
      const float z = sigm(xz.y + az1);
      const float r = sigm(xr.y + ar1);
      const float n = tanhf(xn.y + r * an1);
      st.y = (1.0f - z) * hp.y + z * n;
    }
    hout2[(size_t)j * 64 + lane] = st;
  } else if (ph == 1) {
    const float* tb = dir ? tbb : tbf;
    const float bz = tb[j], br = tb[512 + j], bn = tb[1024 + j];
    float2 st;
    {
      const float z = sigm(az0 + bz);
      const float r = sigm(ar0 + br);
      const float n = tanhf(r * (an0 + bn));
      st.x = (1.0f - z) * hc.x + z * n;
    }
    {
      const float z = sigm(az1 + bz);
      const float r = sigm(ar1 + br);
      const float n = tanhf(r * (an1 + bn));
      st.y = (1.0f - z) * hc.y + z * n;
    }
    hout2[(size_t)j * 64 + lane] = st;
  } else {
    const float* tb = dir ? tbb : tbf;
    const float bz = tb[G_ + j], br = tb[G_ + 512 + j], bn = tb[G_ + 1024 + j];
    float hin0, hin1;
    {
      const float z = sigm(az0 + bz);
      const float r = sigm(ar0 + br);
      const float n = tanhf(r * (an0 + bn));
      hin0 = (1.0f - z) * hc.x + z * n;
    }
    {
      const float z = sigm(az1 + bz);
      const float r = sigm(ar1 + br);
      const float n = tanhf(r * (an1 + bn));
      hin1 = (1.0f - z) * hc.y + z * n;
    }
    const float hn0 = mv.x * hin0 + (1.0f - mv.x) * hp.x;
    const float hn1 = mv.y * hin1 + (1.0f - mv.y) * hp.y;
    float2 st; st.x = hn0; st.y = hn1;
    hout2[(size_t)j * 64 + lane] = st;               // hout == hstate
    OUTS[c2 * 128 + b0]     = hn0 * mv.x;
    OUTS[c2 * 128 + b0 + 1] = hn1 * mv.y;
    __syncthreads();
    if (t < B_) {
      float4 o;
      o.x = OUTS[0 * 128 + t];
      o.y = OUTS[1 * 128 + t];
      o.z = OUTS[2 * 128 + t];
      o.w = OUTS[3 * 128 + t];
      *(float4*)(&outp[((size_t)l * B_ + t) * 1024 + dir * 512 + J0]) = o;
    }
  }
}

// ---------------------------------------------------------------------------
extern "C" void kernel_launch(void* const* d_in, const int* in_sizes, int n_in,
                              void* d_out, int out_size, void* d_ws, size_t ws_size,
                              hipStream_t stream) {
  const int*   xs   = (const int*)d_in[0];
  const float* mask = (const float*)d_in[1];
  const float* emb  = (const float*)d_in[2];
  const float* fWx  = (const float*)d_in[3];
  const float* fUh  = (const float*)d_in[4];
  const float* fb   = (const float*)d_in[5];
  const float* bWx  = (const float*)d_in[6];
  const float* bUh  = (const float*)d_in[7];
  const float* bb   = (const float*)d_in[8];
  const float* ftU  = (const float*)d_in[9];
  const float* ftb  = (const float*)d_in[10];
  const float* btU  = (const float*)d_in[11];
  const float* btb  = (const float*)d_in[12];
  float* out = (float*)d_out;

  // ws: gxT[2][256][1536][128] | hstate | htmp1 | htmp2 | (optional) wp
  float* gxT    = (float*)d_ws;
  float* hstate = gxT + (size_t)2 * L_ * G_ * B_;
  float* htmp1  = hstate + (size_t)2 * H_ * B_;
  float* htmp2  = htmp1 + (size_t)2 * H_ * B_;
  float* wp_buf = htmp2 + (size_t)2 * H_ * B_;

  const size_t need_wp = ((size_t)2 * L_ * G_ * B_ + (size_t)6 * H_ * B_ +
                          (size_t)2 * 3 * 128 * 6144) * sizeof(float);
  const float* wpp = (ws_size >= need_wp) ? wp_buf : nullptr;

  // zero initial h (replay-safe)
  hipMemsetAsync(hstate, 0, (size_t)2 * H_ * B_ * sizeof(float), stream);

  if (wpp != nullptr) {
    dim3 gW(128, 3, 2);
    wprep_kernel<<<gW, 256, 0, stream>>>(fUh, bUh, ftU, btU, wp_buf);
  }

  dim3 gA(G_ / 128, L_, 2);
  gx_kernel<<<gA, 256, 0, stream>>>(xs, emb, fWx, fb, bWx, bb, gxT);

  for (int step = 0; step < L_; ++step) {
    rec_phase<<<256, 256, 0, stream>>>(gxT, mask, fUh, bUh, ftU, btU, ftb, btb,
                                       hstate, htmp1, hstate, wpp, out, step, 0);
    rec_phase<<<256, 256, 0, stream>>>(gxT, mask, fUh, bUh, ftU, btU, ftb, btb,
                                       htmp1, htmp2, hstate, wpp, out, step, 1);
    rec_phase<<<256, 256, 0, stream>>>(gxT, mask, fUh, bUh, ftU, btU, ftb, btb,
                                       htmp2, hstate, hstate, wpp, out, step, 2);
  }
}